// Round 6
// baseline (324.138 us; speedup 1.0000x reference)
//
#include <hip/hip_runtime.h>
#include <math.h>

#define NEG_SLOPE 0.2f

static __device__ __forceinline__ float leaky(float v){ return v > 0.f ? v : NEG_SLOPE * v; }

// ---------------- CSR build ----------------
__global__ void hist_k(const int* __restrict__ edst, int* __restrict__ deg, int Eg, int Etot){
  int e = blockIdx.x * blockDim.x + threadIdx.x;
  if (e >= Etot) return;
  int d = (e < Eg) ? edst[e] : (e - Eg);
  atomicAdd(&deg[d], 1);
}

// A: per-block sums (2048 elems / 256-thread block)
__global__ void __launch_bounds__(256) scan_part_k(const int* __restrict__ deg,
                                                   int* __restrict__ bsum, int N){
  __shared__ int red[256];
  const int t = threadIdx.x;
  const int base = blockIdx.x * 2048;
  int sum = 0;
  #pragma unroll
  for (int i = 0; i < 8; ++i){
    int idx = base + t + i * 256;
    if (idx < N) sum += deg[idx];
  }
  red[t] = sum; __syncthreads();
  #pragma unroll
  for (int d = 128; d; d >>= 1){
    if (t < d) red[t] += red[t + d];
    __syncthreads();
  }
  if (t == 0) bsum[blockIdx.x] = red[0];
}

// B: one wave scans the block sums (nb <= 64)
__global__ void scan_tops_k(const int* __restrict__ bsum, int* __restrict__ boff,
                            int* __restrict__ row, int nb, int N){
  int t = threadIdx.x;
  int v = (t < nb) ? bsum[t] : 0;
  int orig = v;
  #pragma unroll
  for (int off = 1; off < 64; off <<= 1){
    int u = __shfl_up(v, off, 64);
    if (t >= off) v += u;
  }
  if (t < nb) boff[t] = v - orig;
  if (t == nb - 1) row[N] = v;
}

// C: per-block local exclusive scan + global offset, write row & cursor
__global__ void __launch_bounds__(256) scan_write_k(const int* __restrict__ deg,
                                                    const int* __restrict__ boff,
                                                    int* __restrict__ row, int* __restrict__ cursor, int N){
  __shared__ int sdeg[2048];
  __shared__ int tsum[256];
  const int t = threadIdx.x;
  const int base = blockIdx.x * 2048;
  for (int i = t; i < 2048; i += 256){
    int idx = base + i;
    sdeg[i] = (idx < N) ? deg[idx] : 0;
  }
  __syncthreads();
  const int off = t * 8;
  int sum = 0;
  #pragma unroll
  for (int i = 0; i < 8; ++i) sum += sdeg[off + i];
  tsum[t] = sum; __syncthreads();
  for (int d = 1; d < 256; d <<= 1){
    int v = (t >= d) ? tsum[t - d] : 0;
    __syncthreads();
    tsum[t] += v;
    __syncthreads();
  }
  int run = boff[blockIdx.x] + ((t == 0) ? 0 : tsum[t - 1]);
  #pragma unroll
  for (int i = 0; i < 8; ++i){
    int idx = base + off + i;
    if (idx < N){ row[idx] = run; cursor[idx] = run; run += sdeg[off + i]; }
  }
}

__global__ void scatter_k(const int* __restrict__ esrc, const int* __restrict__ edst,
                          int* __restrict__ cursor, int* __restrict__ csr_src, int Eg, int Etot){
  int e = blockIdx.x * blockDim.x + threadIdx.x;
  if (e >= Etot) return;
  int s, d;
  if (e < Eg){ s = esrc[e]; d = edst[e]; } else { s = d = e - Eg; }
  int pos = atomicAdd(&cursor[d], 1);
  csr_src[pos] = s;
}

// ---------------- layer 1 (Fin = 1, rank-1) ----------------
__global__ void dots1_k(const float* __restrict__ W1, const float* __restrict__ a_s,
                        const float* __restrict__ a_d, float* __restrict__ dAdD){
  int t = threadIdx.x;
  float ps = W1[t] * a_s[t];
  float pd = W1[t] * a_d[t];
  #pragma unroll
  for (int off = 16; off; off >>= 1){
    ps += __shfl_xor(ps, off, 32);
    pd += __shfl_xor(pd, off, 32);
  }
  if ((t & 31) == 0){ dAdD[t >> 5] = ps; dAdD[4 + (t >> 5)] = pd; }
}

// Rank-1 layer-1 GAT: out[n][h*32+c] = W1[h*32+c] * (sum_e p_e x[src_e])/s_h + b1, ELU.
__global__ void __launch_bounds__(256) node_aggr1_k(const int* __restrict__ row, const int* __restrict__ csr_src,
                                                    const float* __restrict__ x, const float* __restrict__ dAdD,
                                                    const float4* __restrict__ W1_4, const float4* __restrict__ b1_4,
                                                    float4* __restrict__ out4, int N){
  int node = blockIdx.x * 8 + (threadIdx.x >> 5);
  if (node >= N) return;
  const int j = threadIdx.x & 31;
  const int start = row[node], end = row[node + 1];
  const float xd = x[node];
  float dA0 = dAdD[0], dA1 = dAdD[1], dA2 = dAdD[2], dA3 = dAdD[3];
  float e0d = xd * dAdD[4], e1d = xd * dAdD[5], e2d = xd * dAdD[6], e3d = xd * dAdD[7];

  float s0 = 0.f, s1 = 0.f, s2 = 0.f, s3 = 0.f;
  float t0 = 0.f, t1 = 0.f, t2 = 0.f, t3 = 0.f;
  for (int i = start + j; i < end; i += 32){
    float xs = x[csr_src[i]];
    float p0 = __expf(leaky(xs * dA0 + e0d));
    float p1 = __expf(leaky(xs * dA1 + e1d));
    float p2 = __expf(leaky(xs * dA2 + e2d));
    float p3 = __expf(leaky(xs * dA3 + e3d));
    s0 += p0; s1 += p1; s2 += p2; s3 += p3;
    t0 += p0 * xs; t1 += p1 * xs; t2 += p2 * xs; t3 += p3 * xs;
  }
  #pragma unroll
  for (int off = 16; off; off >>= 1){
    s0 += __shfl_xor(s0, off, 32); t0 += __shfl_xor(t0, off, 32);
    s1 += __shfl_xor(s1, off, 32); t1 += __shfl_xor(t1, off, 32);
    s2 += __shfl_xor(s2, off, 32); t2 += __shfl_xor(t2, off, 32);
    s3 += __shfl_xor(s3, off, 32); t3 += __shfl_xor(t3, off, 32);
  }
  const int hd = j >> 3;
  float r = (hd == 0) ? t0 / s0 : (hd == 1) ? t1 / s1 : (hd == 2) ? t2 / s2 : t3 / s3;
  float4 w = W1_4[j], b = b1_4[j];
  float4 v;
  v.x = w.x * r + b.x;
  v.y = w.y * r + b.y;
  v.z = w.z * r + b.z;
  v.w = w.w * r + b.w;
  v.x = v.x > 0.f ? v.x : expm1f(v.x);
  v.y = v.y > 0.f ? v.y : expm1f(v.y);
  v.z = v.z > 0.f ? v.z : expm1f(v.z);
  v.w = v.w > 0.f ? v.w : expm1f(v.w);
  out4[(size_t)node * 32 + j] = v;
}

// ---------------- per-node aggregate, layer 2 ----------------
// 32 threads per node; lane j owns channels 4j..4j+3 (head = j>>3).
// Single pass, no max (bounded logits), __expf. 8-edge unroll with int4 idx
// loads and all gathers issued before use (MLP for L2/L3 latency).
template<bool DO_ELU>
__global__ void __launch_bounds__(256) node_aggr_k(const int* __restrict__ row, const int* __restrict__ csr_src,
                                                   const float* __restrict__ as_, const float* __restrict__ ad_,
                                                   const float4* __restrict__ h4, const float4* __restrict__ bias4,
                                                   float4* __restrict__ out4, int N){
  int node = blockIdx.x * 8 + (threadIdx.x >> 5);
  if (node >= N) return;
  const int j  = threadIdx.x & 31;
  const int hd = j >> 3;
  const int start = row[node], end = row[node + 1];
  const float adv = ad_[node * 4 + hd];

  float s = 0.f;
  float4 acc = make_float4(0.f, 0.f, 0.f, 0.f);
  int i = start;

  // prologue: align i to a multiple of 4 (csr_src is 16B-aligned)
  int pre = (4 - (start & 3)) & 3;
  if (pre > end - start) pre = end - start;
  for (int k = 0; k < pre; ++k, ++i){
    int src = csr_src[i];
    float p = __expf(leaky(as_[src*4 + hd] + adv));
    float4 hv = h4[(size_t)src*32 + j];
    s += p;
    acc.x += hv.x*p; acc.y += hv.y*p; acc.z += hv.z*p; acc.w += hv.w*p;
  }

  // main: 8 edges per iter, two int4 idx loads, gathers batched
  for (; i + 8 <= end; i += 8){
    int4 ia = *(const int4*)&csr_src[i];
    int4 ib = *(const int4*)&csr_src[i + 4];
    float a0 = as_[ia.x*4 + hd], a1 = as_[ia.y*4 + hd], a2 = as_[ia.z*4 + hd], a3 = as_[ia.w*4 + hd];
    float a4 = as_[ib.x*4 + hd], a5 = as_[ib.y*4 + hd], a6 = as_[ib.z*4 + hd], a7 = as_[ib.w*4 + hd];
    float4 h0 = h4[(size_t)ia.x*32 + j];
    float4 h1 = h4[(size_t)ia.y*32 + j];
    float4 h2 = h4[(size_t)ia.z*32 + j];
    float4 h3 = h4[(size_t)ia.w*32 + j];
    float4 h5 = h4[(size_t)ib.x*32 + j];
    float4 h6 = h4[(size_t)ib.y*32 + j];
    float4 h7 = h4[(size_t)ib.z*32 + j];
    float4 h8 = h4[(size_t)ib.w*32 + j];
    float p0 = __expf(leaky(a0 + adv));
    float p1 = __expf(leaky(a1 + adv));
    float p2 = __expf(leaky(a2 + adv));
    float p3 = __expf(leaky(a3 + adv));
    float p4 = __expf(leaky(a4 + adv));
    float p5 = __expf(leaky(a5 + adv));
    float p6 = __expf(leaky(a6 + adv));
    float p7 = __expf(leaky(a7 + adv));
    s += ((p0 + p1) + (p2 + p3)) + ((p4 + p5) + (p6 + p7));
    acc.x += (h0.x*p0 + h1.x*p1 + h2.x*p2 + h3.x*p3) + (h5.x*p4 + h6.x*p5 + h7.x*p6 + h8.x*p7);
    acc.y += (h0.y*p0 + h1.y*p1 + h2.y*p2 + h3.y*p3) + (h5.y*p4 + h6.y*p5 + h7.y*p6 + h8.y*p7);
    acc.z += (h0.z*p0 + h1.z*p1 + h2.z*p2 + h3.z*p3) + (h5.z*p4 + h6.z*p5 + h7.z*p6 + h8.z*p7);
    acc.w += (h0.w*p0 + h1.w*p1 + h2.w*p2 + h3.w*p3) + (h5.w*p4 + h6.w*p5 + h7.w*p6 + h8.w*p7);
  }
  // 4-edge step
  for (; i + 4 <= end; i += 4){
    int4 ia = *(const int4*)&csr_src[i];
    float a0 = as_[ia.x*4 + hd], a1 = as_[ia.y*4 + hd], a2 = as_[ia.z*4 + hd], a3 = as_[ia.w*4 + hd];
    float4 h0 = h4[(size_t)ia.x*32 + j];
    float4 h1 = h4[(size_t)ia.y*32 + j];
    float4 h2 = h4[(size_t)ia.z*32 + j];
    float4 h3 = h4[(size_t)ia.w*32 + j];
    float p0 = __expf(leaky(a0 + adv));
    float p1 = __expf(leaky(a1 + adv));
    float p2 = __expf(leaky(a2 + adv));
    float p3 = __expf(leaky(a3 + adv));
    s += (p0 + p1) + (p2 + p3);
    acc.x += h0.x*p0 + h1.x*p1 + h2.x*p2 + h3.x*p3;
    acc.y += h0.y*p0 + h1.y*p1 + h2.y*p2 + h3.y*p3;
    acc.z += h0.z*p0 + h1.z*p1 + h2.z*p2 + h3.z*p3;
    acc.w += h0.w*p0 + h1.w*p1 + h2.w*p2 + h3.w*p3;
  }
  // tail
  for (; i < end; ++i){
    int src = csr_src[i];
    float p = __expf(leaky(as_[src*4 + hd] + adv));
    float4 hv = h4[(size_t)src*32 + j];
    s += p;
    acc.x += hv.x*p; acc.y += hv.y*p; acc.z += hv.z*p; acc.w += hv.w*p;
  }

  float inv = 1.f / s;
  float4 b = bias4[j];
  float4 v;
  v.x = acc.x * inv + b.x;
  v.y = acc.y * inv + b.y;
  v.z = acc.z * inv + b.z;
  v.w = acc.w * inv + b.w;
  if (DO_ELU){
    v.x = v.x > 0.f ? v.x : expm1f(v.x);
    v.y = v.y > 0.f ? v.y : expm1f(v.y);
    v.z = v.z > 0.f ? v.z : expm1f(v.z);
    v.w = v.w > 0.f ? v.w : expm1f(v.w);
  }
  out4[(size_t)node * 32 + j] = v;
}

// ---------------- layer 2 dense: h = A(Nx128) * W(128x128), alphas fused ----------------
__global__ void __launch_bounds__(256) gemm2_k(const float* __restrict__ A, const float* __restrict__ W,
                                               const float* __restrict__ a_s, const float* __restrict__ a_d,
                                               float* __restrict__ h, float* __restrict__ as_, float* __restrict__ ad_,
                                               int N){
  __shared__ float sA[2][16][68];    // [buf][k][row] transposed, padded
  __shared__ float sW[2][16][128];   // [buf][k][col]
  const int t = threadIdx.x;
  const int n0 = blockIdx.x * 64;
  const int tx = t & 15, ty = t >> 4;
  const int c0 = tx * 8, r0 = ty * 4;

  const int lr = t >> 2;         // 0..63: A row within tile
  const int lg = t & 3;          // A k-quad
  const int wk = t >> 5;         // 0..7: W k row
  const int wq = t & 31;         // W col-quad

  float4 ra, rw0, rw1;
  const int grA = n0 + lr;
  auto gload = [&](int k0){
    ra  = (grA < N) ? *(const float4*)&A[(size_t)grA * 128 + k0 + lg * 4] : make_float4(0.f,0.f,0.f,0.f);
    rw0 = *(const float4*)&W[(size_t)(k0 + wk) * 128 + wq * 4];
    rw1 = *(const float4*)&W[(size_t)(k0 + wk + 8) * 128 + wq * 4];
  };
  auto sstore = [&](int buf){
    sA[buf][lg*4 + 0][lr] = ra.x;
    sA[buf][lg*4 + 1][lr] = ra.y;
    sA[buf][lg*4 + 2][lr] = ra.z;
    sA[buf][lg*4 + 3][lr] = ra.w;
    *(float4*)&sW[buf][wk][wq*4]     = rw0;
    *(float4*)&sW[buf][wk + 8][wq*4] = rw1;
  };

  float acc[4][8];
  #pragma unroll
  for (int r = 0; r < 4; ++r)
    #pragma unroll
    for (int c = 0; c < 8; ++c) acc[r][c] = 0.f;

  gload(0); sstore(0); __syncthreads();

  #pragma unroll 1
  for (int tile = 0; tile < 8; ++tile){
    const int buf = tile & 1;
    if (tile < 7) gload((tile + 1) * 16);
    #pragma unroll
    for (int k = 0; k < 16; ++k){
      float4 aa = *(const float4*)&sA[buf][k][r0];
      float4 w0 = *(const float4*)&sW[buf][k][c0];
      float4 w1 = *(const float4*)&sW[buf][k][c0 + 4];
      float av[4] = {aa.x, aa.y, aa.z, aa.w};
      float wv[8] = {w0.x, w0.y, w0.z, w0.w, w1.x, w1.y, w1.z, w1.w};
      #pragma unroll
      for (int r = 0; r < 4; ++r)
        #pragma unroll
        for (int c = 0; c < 8; ++c) acc[r][c] += av[r] * wv[c];
    }
    if (tile < 7){ sstore(1 - buf); __syncthreads(); }
  }

  float asv[8], adv[8];
  #pragma unroll
  for (int c = 0; c < 8; ++c){ asv[c] = a_s[c0 + c]; adv[c] = a_d[c0 + c]; }

  #pragma unroll
  for (int r = 0; r < 4; ++r){
    int n = n0 + r0 + r;
    if (n >= N) continue;
    float4 o0 = make_float4(acc[r][0], acc[r][1], acc[r][2], acc[r][3]);
    float4 o1 = make_float4(acc[r][4], acc[r][5], acc[r][6], acc[r][7]);
    float4* hp = (float4*)&h[(size_t)n * 128 + c0];
    hp[0] = o0; hp[1] = o1;
    float ps = 0.f, pd = 0.f;
    #pragma unroll
    for (int c = 0; c < 8; ++c){ ps += acc[r][c] * asv[c]; pd += acc[r][c] * adv[c]; }
    ps += __shfl_xor(ps, 1); ps += __shfl_xor(ps, 2);
    pd += __shfl_xor(pd, 1); pd += __shfl_xor(pd, 2);
    if ((tx & 3) == 0){
      as_[n * 4 + (tx >> 2)] = ps;
      ad_[n * 4 + (tx >> 2)] = pd;
    }
  }
}

// ---------------- layer 3 ----------------
__global__ void __launch_bounds__(256) transform3_k(const float* __restrict__ A, const float* __restrict__ W3,
                                                    const float* __restrict__ a_s3, const float* __restrict__ a_d3,
                                                    float* __restrict__ h3, float* __restrict__ as_, float* __restrict__ ad_,
                                                    int N){
  int node = blockIdx.x * 8 + (threadIdx.x >> 5);
  if (node >= N) return;
  int j = threadIdx.x & 31;
  float4 a = ((const float4*)A)[(size_t)node * 32 + j];
  float4 w = ((const float4*)W3)[j];
  float acc = a.x * w.x + a.y * w.y + a.z * w.z + a.w * w.w;
  #pragma unroll
  for (int off = 16; off; off >>= 1) acc += __shfl_xor(acc, off, 32);
  if (j == 0){
    h3[node]  = acc;
    as_[node] = acc * a_s3[0];
    ad_[node] = acc * a_d3[0];
  }
}

// single pass, no max, 64 lanes per node
__global__ void __launch_bounds__(256) node_aggr3_k(const int* __restrict__ row, const int* __restrict__ csr_src,
                                                    const float* __restrict__ as_, const float* __restrict__ ad_,
                                                    const float* __restrict__ h3, const float* __restrict__ b3,
                                                    float* __restrict__ out, int N){
  int node = blockIdx.x * 4 + (threadIdx.x >> 6);
  if (node >= N) return;
  int j = threadIdx.x & 63;
  int start = row[node], end = row[node + 1];
  float adv = ad_[node];
  float s = 0.f, acc = 0.f;
  for (int i = start + j; i < end; i += 64){
    int src = csr_src[i];
    float p = __expf(leaky(as_[src] + adv));
    s += p; acc += h3[src] * p;
  }
  #pragma unroll
  for (int off = 32; off; off >>= 1){ s += __shfl_xor(s, off); acc += __shfl_xor(acc, off); }
  if (j == 0) out[node] = acc / s + b3[0];
}

// ---------------- launch ----------------
extern "C" void kernel_launch(void* const* d_in, const int* in_sizes, int n_in,
                              void* d_out, int out_size, void* d_ws, size_t ws_size,
                              hipStream_t stream){
  const float* x   = (const float*)d_in[0];
  const int*   ei  = (const int*)  d_in[1];
  const float* W1  = (const float*)d_in[2];
  const float* as1 = (const float*)d_in[3];
  const float* ad1 = (const float*)d_in[4];
  const float* b1  = (const float*)d_in[5];
  const float* W2  = (const float*)d_in[6];
  const float* as2 = (const float*)d_in[7];
  const float* ad2 = (const float*)d_in[8];
  const float* b2  = (const float*)d_in[9];
  const float* W3  = (const float*)d_in[10];
  const float* as3 = (const float*)d_in[11];
  const float* ad3 = (const float*)d_in[12];
  const float* b3  = (const float*)d_in[13];

  const int N    = in_sizes[0];       // IN_C = 1
  const int Eg   = in_sizes[1] / 2;
  const int Etot = Eg + N;
  const int* esrc = ei;
  const int* edst = ei + Eg;

  char* w = (char*)d_ws;
  auto carve = [&](size_t bytes)->char*{
    char* p = w; w += (bytes + 15) & ~size_t(15); return p;
  };
  float* hbuf   = (float*)carve((size_t)N * 128 * 4);
  float* actA   = (float*)carve((size_t)N * 128 * 4);
  float* asb    = (float*)carve((size_t)N * 4 * 4);
  float* adb    = (float*)carve((size_t)N * 4 * 4);
  float* h3b    = (float*)carve((size_t)N * 4);
  float* as3b   = (float*)carve((size_t)N * 4);
  float* ad3b   = (float*)carve((size_t)N * 4);
  int*   deg    = (int*)  carve((size_t)N * 4);
  int*   rowp   = (int*)  carve((size_t)(N + 1) * 4);
  int*   cursor = (int*)  carve((size_t)N * 4);
  int*   csr_src= (int*)  carve((size_t)Etot * 4);
  float* dAdD   = (float*)carve(8 * 4);
  int*   bsum   = (int*)  carve(64 * 4);
  int*   boff   = (int*)  carve(64 * 4);

  const int B = 256;
  auto cdiv = [](int a, int b){ return (a + b - 1) / b; };
  const int nb = cdiv(N, 2048);   // 25 for N=50000 (must be <= 64)

  // ---- CSR build (shared by all 3 layers) ----
  hipMemsetAsync(deg, 0, (size_t)N * 4, stream);
  hist_k<<<cdiv(Etot, B), B, 0, stream>>>(edst, deg, Eg, Etot);
  scan_part_k<<<nb, B, 0, stream>>>(deg, bsum, N);
  scan_tops_k<<<1, 64, 0, stream>>>(bsum, boff, rowp, nb, N);
  scan_write_k<<<nb, B, 0, stream>>>(deg, boff, rowp, cursor, N);
  scatter_k<<<cdiv(Etot, B), B, 0, stream>>>(esrc, edst, cursor, csr_src, Eg, Etot);

  // ---- layer 1 (rank-1: no transform, scalar gather) ----
  dots1_k<<<1, 128, 0, stream>>>(W1, as1, ad1, dAdD);
  node_aggr1_k<<<cdiv(N, 8), B, 0, stream>>>(rowp, csr_src, x, dAdD,
                                             (const float4*)W1, (const float4*)b1,
                                             (float4*)actA, N);

  // ---- layer 2 ----
  gemm2_k<<<cdiv(N, 64), B, 0, stream>>>(actA, W2, as2, ad2, hbuf, asb, adb, N);
  node_aggr_k<true><<<cdiv(N, 8), B, 0, stream>>>(rowp, csr_src, asb, adb,
                                                  (const float4*)hbuf, (const float4*)b2,
                                                  (float4*)actA, N);

  // ---- layer 3 (H=1, C=1) ----
  transform3_k<<<cdiv(N, 8), B, 0, stream>>>(actA, W3, as3, ad3, h3b, as3b, ad3b, N);
  node_aggr3_k<<<cdiv(N, 4), B, 0, stream>>>(rowp, csr_src, as3b, ad3b, h3b, b3, (float*)d_out, N);
}

// Round 7
// 315.496 us; speedup vs baseline: 1.0274x; 1.0274x over previous
//
#include <hip/hip_runtime.h>
#include <math.h>

#define NEG_SLOPE 0.2f

static __device__ __forceinline__ float leaky(float v){ return v > 0.f ? v : NEG_SLOPE * v; }

// ---------------- CSR build ----------------
__global__ void hist_k(const int* __restrict__ edst, int* __restrict__ deg, int Eg, int Etot){
  int e = blockIdx.x * blockDim.x + threadIdx.x;
  if (e >= Etot) return;
  int d = (e < Eg) ? edst[e] : (e - Eg);
  atomicAdd(&deg[d], 1);
}

// A: per-block sums (2048 elems / 256-thread block)
__global__ void __launch_bounds__(256) scan_part_k(const int* __restrict__ deg,
                                                   int* __restrict__ bsum, int N){
  __shared__ int red[256];
  const int t = threadIdx.x;
  const int base = blockIdx.x * 2048;
  int sum = 0;
  #pragma unroll
  for (int i = 0; i < 8; ++i){
    int idx = base + t + i * 256;
    if (idx < N) sum += deg[idx];
  }
  red[t] = sum; __syncthreads();
  #pragma unroll
  for (int d = 128; d; d >>= 1){
    if (t < d) red[t] += red[t + d];
    __syncthreads();
  }
  if (t == 0) bsum[blockIdx.x] = red[0];
}

// B: one wave scans the block sums (nb <= 64)
__global__ void scan_tops_k(const int* __restrict__ bsum, int* __restrict__ boff,
                            int* __restrict__ row, int nb, int N){
  int t = threadIdx.x;
  int v = (t < nb) ? bsum[t] : 0;
  int orig = v;
  #pragma unroll
  for (int off = 1; off < 64; off <<= 1){
    int u = __shfl_up(v, off, 64);
    if (t >= off) v += u;
  }
  if (t < nb) boff[t] = v - orig;
  if (t == nb - 1) row[N] = v;
}

// C: per-block local exclusive scan + global offset, write row & cursor
__global__ void __launch_bounds__(256) scan_write_k(const int* __restrict__ deg,
                                                    const int* __restrict__ boff,
                                                    int* __restrict__ row, int* __restrict__ cursor, int N){
  __shared__ int sdeg[2048];
  __shared__ int tsum[256];
  const int t = threadIdx.x;
  const int base = blockIdx.x * 2048;
  for (int i = t; i < 2048; i += 256){
    int idx = base + i;
    sdeg[i] = (idx < N) ? deg[idx] : 0;
  }
  __syncthreads();
  const int off = t * 8;
  int sum = 0;
  #pragma unroll
  for (int i = 0; i < 8; ++i) sum += sdeg[off + i];
  tsum[t] = sum; __syncthreads();
  for (int d = 1; d < 256; d <<= 1){
    int v = (t >= d) ? tsum[t - d] : 0;
    __syncthreads();
    tsum[t] += v;
    __syncthreads();
  }
  int run = boff[blockIdx.x] + ((t == 0) ? 0 : tsum[t - 1]);
  #pragma unroll
  for (int i = 0; i < 8; ++i){
    int idx = base + off + i;
    if (idx < N){ row[idx] = run; cursor[idx] = run; run += sdeg[off + i]; }
  }
}

__global__ void scatter_k(const int* __restrict__ esrc, const int* __restrict__ edst,
                          int* __restrict__ cursor, int* __restrict__ csr_src, int Eg, int Etot){
  int e = blockIdx.x * blockDim.x + threadIdx.x;
  if (e >= Etot) return;
  int s, d;
  if (e < Eg){ s = esrc[e]; d = edst[e]; } else { s = d = e - Eg; }
  int pos = atomicAdd(&cursor[d], 1);
  csr_src[pos] = s;
}

// ---------------- layer 1 (Fin = 1, rank-1) ----------------
__global__ void dots1_k(const float* __restrict__ W1, const float* __restrict__ a_s,
                        const float* __restrict__ a_d, float* __restrict__ dAdD){
  int t = threadIdx.x;
  float ps = W1[t] * a_s[t];
  float pd = W1[t] * a_d[t];
  #pragma unroll
  for (int off = 16; off; off >>= 1){
    ps += __shfl_xor(ps, off, 32);
    pd += __shfl_xor(pd, off, 32);
  }
  if ((t & 31) == 0){ dAdD[t >> 5] = ps; dAdD[4 + (t >> 5)] = pd; }
}

// Rank-1 layer-1 GAT: out[n][h*32+c] = W1[h*32+c] * (sum_e p_e x[src_e])/s_h + b1, ELU.
__global__ void __launch_bounds__(256) node_aggr1_k(const int* __restrict__ row, const int* __restrict__ csr_src,
                                                    const float* __restrict__ x, const float* __restrict__ dAdD,
                                                    const float4* __restrict__ W1_4, const float4* __restrict__ b1_4,
                                                    float4* __restrict__ out4, int N){
  int node = blockIdx.x * 8 + (threadIdx.x >> 5);
  if (node >= N) return;
  const int j = threadIdx.x & 31;
  const int start = row[node], end = row[node + 1];
  const float xd = x[node];
  float dA0 = dAdD[0], dA1 = dAdD[1], dA2 = dAdD[2], dA3 = dAdD[3];
  float e0d = xd * dAdD[4], e1d = xd * dAdD[5], e2d = xd * dAdD[6], e3d = xd * dAdD[7];

  float s0 = 0.f, s1 = 0.f, s2 = 0.f, s3 = 0.f;
  float t0 = 0.f, t1 = 0.f, t2 = 0.f, t3 = 0.f;
  for (int i = start + j; i < end; i += 32){
    float xs = x[csr_src[i]];
    float p0 = __expf(leaky(xs * dA0 + e0d));
    float p1 = __expf(leaky(xs * dA1 + e1d));
    float p2 = __expf(leaky(xs * dA2 + e2d));
    float p3 = __expf(leaky(xs * dA3 + e3d));
    s0 += p0; s1 += p1; s2 += p2; s3 += p3;
    t0 += p0 * xs; t1 += p1 * xs; t2 += p2 * xs; t3 += p3 * xs;
  }
  #pragma unroll
  for (int off = 16; off; off >>= 1){
    s0 += __shfl_xor(s0, off, 32); t0 += __shfl_xor(t0, off, 32);
    s1 += __shfl_xor(s1, off, 32); t1 += __shfl_xor(t1, off, 32);
    s2 += __shfl_xor(s2, off, 32); t2 += __shfl_xor(t2, off, 32);
    s3 += __shfl_xor(s3, off, 32); t3 += __shfl_xor(t3, off, 32);
  }
  const int hd = j >> 3;
  float r = (hd == 0) ? t0 / s0 : (hd == 1) ? t1 / s1 : (hd == 2) ? t2 / s2 : t3 / s3;
  float4 w = W1_4[j], b = b1_4[j];
  float4 v;
  v.x = w.x * r + b.x;
  v.y = w.y * r + b.y;
  v.z = w.z * r + b.z;
  v.w = w.w * r + b.w;
  v.x = v.x > 0.f ? v.x : expm1f(v.x);
  v.y = v.y > 0.f ? v.y : expm1f(v.y);
  v.z = v.z > 0.f ? v.z : expm1f(v.z);
  v.w = v.w > 0.f ? v.w : expm1f(v.w);
  out4[(size_t)node * 32 + j] = v;
}

// ---------------- per-node aggregate, layer 2: HEAD-SPLIT + XCD-pinned ----------------
// grid.x = cdiv(N,64)*8.  slot = blockIdx&7 (→ XCD via the %8 dispatch heuristic):
// head = slot>>1, parity = slot&1. Each block: 32 nodes × 8 lanes; lane q owns
// channels [head*32 + q*4 .. +4). Per-XCD unique h footprint drops 25.6→6.4 MB.
template<bool DO_ELU>
__global__ void __launch_bounds__(256) node_aggr2_k(const int* __restrict__ row, const int* __restrict__ csr_src,
                                                    const float* __restrict__ as_, const float* __restrict__ ad_,
                                                    const float4* __restrict__ h4, const float4* __restrict__ bias4,
                                                    float4* __restrict__ out4, int N){
  const int slot   = blockIdx.x & 7;
  const int chunk  = blockIdx.x >> 3;
  const int head   = slot >> 1;
  const int parity = slot & 1;
  const int t  = threadIdx.x;
  const int nl = t >> 3;          // node slot 0..31
  const int q  = t & 7;           // lane within head
  const int node = chunk * 64 + parity * 32 + nl;
  if (node >= N) return;
  const int start = row[node], end = row[node + 1];
  const float adv = ad_[node * 4 + head];
  const int cix = head * 8 + q;   // float4 index within a 32-float4 row

  float s = 0.f;
  float4 acc = make_float4(0.f, 0.f, 0.f, 0.f);
  int i = start;

  // prologue: align i to a multiple of 4 (csr_src is 16B-aligned)
  int pre = (4 - (start & 3)) & 3;
  if (pre > end - start) pre = end - start;
  for (int k = 0; k < pre; ++k, ++i){
    int src = csr_src[i];
    float p = __expf(leaky(as_[src*4 + head] + adv));
    float4 hv = h4[(size_t)src*32 + cix];
    s += p;
    acc.x += hv.x*p; acc.y += hv.y*p; acc.z += hv.z*p; acc.w += hv.w*p;
  }
  // main: 4 edges per iter, int4 idx load, gathers batched
  for (; i + 4 <= end; i += 4){
    int4 ia = *(const int4*)&csr_src[i];
    float a0 = as_[ia.x*4 + head], a1 = as_[ia.y*4 + head];
    float a2 = as_[ia.z*4 + head], a3 = as_[ia.w*4 + head];
    float4 h0 = h4[(size_t)ia.x*32 + cix];
    float4 h1 = h4[(size_t)ia.y*32 + cix];
    float4 h2 = h4[(size_t)ia.z*32 + cix];
    float4 h3 = h4[(size_t)ia.w*32 + cix];
    float p0 = __expf(leaky(a0 + adv));
    float p1 = __expf(leaky(a1 + adv));
    float p2 = __expf(leaky(a2 + adv));
    float p3 = __expf(leaky(a3 + adv));
    s += (p0 + p1) + (p2 + p3);
    acc.x += h0.x*p0 + h1.x*p1 + h2.x*p2 + h3.x*p3;
    acc.y += h0.y*p0 + h1.y*p1 + h2.y*p2 + h3.y*p3;
    acc.z += h0.z*p0 + h1.z*p1 + h2.z*p2 + h3.z*p3;
    acc.w += h0.w*p0 + h1.w*p1 + h2.w*p2 + h3.w*p3;
  }
  // tail
  for (; i < end; ++i){
    int src = csr_src[i];
    float p = __expf(leaky(as_[src*4 + head] + adv));
    float4 hv = h4[(size_t)src*32 + cix];
    s += p;
    acc.x += hv.x*p; acc.y += hv.y*p; acc.z += hv.z*p; acc.w += hv.w*p;
  }

  float inv = 1.f / s;
  float4 b = bias4[cix];
  float4 v;
  v.x = acc.x * inv + b.x;
  v.y = acc.y * inv + b.y;
  v.z = acc.z * inv + b.z;
  v.w = acc.w * inv + b.w;
  if (DO_ELU){
    v.x = v.x > 0.f ? v.x : expm1f(v.x);
    v.y = v.y > 0.f ? v.y : expm1f(v.y);
    v.z = v.z > 0.f ? v.z : expm1f(v.z);
    v.w = v.w > 0.f ? v.w : expm1f(v.w);
  }
  out4[(size_t)node * 32 + cix] = v;
}

// ---------------- layer 2 dense: h = A(Nx128) * W(128x128), alphas fused ----------------
__global__ void __launch_bounds__(256) gemm2_k(const float* __restrict__ A, const float* __restrict__ W,
                                               const float* __restrict__ a_s, const float* __restrict__ a_d,
                                               float* __restrict__ h, float* __restrict__ as_, float* __restrict__ ad_,
                                               int N){
  __shared__ float sA[2][16][68];    // [buf][k][row] transposed, padded
  __shared__ float sW[2][16][128];   // [buf][k][col]
  const int t = threadIdx.x;
  const int n0 = blockIdx.x * 64;
  const int tx = t & 15, ty = t >> 4;
  const int c0 = tx * 8, r0 = ty * 4;

  const int lr = t >> 2;         // 0..63: A row within tile
  const int lg = t & 3;          // A k-quad
  const int wk = t >> 5;         // 0..7: W k row
  const int wq = t & 31;         // W col-quad

  float4 ra, rw0, rw1;
  const int grA = n0 + lr;
  auto gload = [&](int k0){
    ra  = (grA < N) ? *(const float4*)&A[(size_t)grA * 128 + k0 + lg * 4] : make_float4(0.f,0.f,0.f,0.f);
    rw0 = *(const float4*)&W[(size_t)(k0 + wk) * 128 + wq * 4];
    rw1 = *(const float4*)&W[(size_t)(k0 + wk + 8) * 128 + wq * 4];
  };
  auto sstore = [&](int buf){
    sA[buf][lg*4 + 0][lr] = ra.x;
    sA[buf][lg*4 + 1][lr] = ra.y;
    sA[buf][lg*4 + 2][lr] = ra.z;
    sA[buf][lg*4 + 3][lr] = ra.w;
    *(float4*)&sW[buf][wk][wq*4]     = rw0;
    *(float4*)&sW[buf][wk + 8][wq*4] = rw1;
  };

  float acc[4][8];
  #pragma unroll
  for (int r = 0; r < 4; ++r)
    #pragma unroll
    for (int c = 0; c < 8; ++c) acc[r][c] = 0.f;

  gload(0); sstore(0); __syncthreads();

  #pragma unroll 1
  for (int tile = 0; tile < 8; ++tile){
    const int buf = tile & 1;
    if (tile < 7) gload((tile + 1) * 16);
    #pragma unroll
    for (int k = 0; k < 16; ++k){
      float4 aa = *(const float4*)&sA[buf][k][r0];
      float4 w0 = *(const float4*)&sW[buf][k][c0];
      float4 w1 = *(const float4*)&sW[buf][k][c0 + 4];
      float av[4] = {aa.x, aa.y, aa.z, aa.w};
      float wv[8] = {w0.x, w0.y, w0.z, w0.w, w1.x, w1.y, w1.z, w1.w};
      #pragma unroll
      for (int r = 0; r < 4; ++r)
        #pragma unroll
        for (int c = 0; c < 8; ++c) acc[r][c] += av[r] * wv[c];
    }
    if (tile < 7){ sstore(1 - buf); __syncthreads(); }
  }

  float asv[8], adv[8];
  #pragma unroll
  for (int c = 0; c < 8; ++c){ asv[c] = a_s[c0 + c]; adv[c] = a_d[c0 + c]; }

  #pragma unroll
  for (int r = 0; r < 4; ++r){
    int n = n0 + r0 + r;
    if (n >= N) continue;
    float4 o0 = make_float4(acc[r][0], acc[r][1], acc[r][2], acc[r][3]);
    float4 o1 = make_float4(acc[r][4], acc[r][5], acc[r][6], acc[r][7]);
    float4* hp = (float4*)&h[(size_t)n * 128 + c0];
    hp[0] = o0; hp[1] = o1;
    float ps = 0.f, pd = 0.f;
    #pragma unroll
    for (int c = 0; c < 8; ++c){ ps += acc[r][c] * asv[c]; pd += acc[r][c] * adv[c]; }
    ps += __shfl_xor(ps, 1); ps += __shfl_xor(ps, 2);
    pd += __shfl_xor(pd, 1); pd += __shfl_xor(pd, 2);
    if ((tx & 3) == 0){
      as_[n * 4 + (tx >> 2)] = ps;
      ad_[n * 4 + (tx >> 2)] = pd;
    }
  }
}

// ---------------- layer 3 ----------------
__global__ void __launch_bounds__(256) transform3_k(const float* __restrict__ A, const float* __restrict__ W3,
                                                    const float* __restrict__ a_s3, const float* __restrict__ a_d3,
                                                    float* __restrict__ h3, float* __restrict__ as_, float* __restrict__ ad_,
                                                    int N){
  int node = blockIdx.x * 8 + (threadIdx.x >> 5);
  if (node >= N) return;
  int j = threadIdx.x & 31;
  float4 a = ((const float4*)A)[(size_t)node * 32 + j];
  float4 w = ((const float4*)W3)[j];
  float acc = a.x * w.x + a.y * w.y + a.z * w.z + a.w * w.w;
  #pragma unroll
  for (int off = 16; off; off >>= 1) acc += __shfl_xor(acc, off, 32);
  if (j == 0){
    h3[node]  = acc;
    as_[node] = acc * a_s3[0];
    ad_[node] = acc * a_d3[0];
  }
}

// single pass, no max, 64 lanes per node
__global__ void __launch_bounds__(256) node_aggr3_k(const int* __restrict__ row, const int* __restrict__ csr_src,
                                                    const float* __restrict__ as_, const float* __restrict__ ad_,
                                                    const float* __restrict__ h3, const float* __restrict__ b3,
                                                    float* __restrict__ out, int N){
  int node = blockIdx.x * 4 + (threadIdx.x >> 6);
  if (node >= N) return;
  int j = threadIdx.x & 63;
  int start = row[node], end = row[node + 1];
  float adv = ad_[node];
  float s = 0.f, acc = 0.f;
  for (int i = start + j; i < end; i += 64){
    int src = csr_src[i];
    float p = __expf(leaky(as_[src] + adv));
    s += p; acc += h3[src] * p;
  }
  #pragma unroll
  for (int off = 32; off; off >>= 1){ s += __shfl_xor(s, off); acc += __shfl_xor(acc, off); }
  if (j == 0) out[node] = acc / s + b3[0];
}

// ---------------- launch ----------------
extern "C" void kernel_launch(void* const* d_in, const int* in_sizes, int n_in,
                              void* d_out, int out_size, void* d_ws, size_t ws_size,
                              hipStream_t stream){
  const float* x   = (const float*)d_in[0];
  const int*   ei  = (const int*)  d_in[1];
  const float* W1  = (const float*)d_in[2];
  const float* as1 = (const float*)d_in[3];
  const float* ad1 = (const float*)d_in[4];
  const float* b1  = (const float*)d_in[5];
  const float* W2  = (const float*)d_in[6];
  const float* as2 = (const float*)d_in[7];
  const float* ad2 = (const float*)d_in[8];
  const float* b2  = (const float*)d_in[9];
  const float* W3  = (const float*)d_in[10];
  const float* as3 = (const float*)d_in[11];
  const float* ad3 = (const float*)d_in[12];
  const float* b3  = (const float*)d_in[13];

  const int N    = in_sizes[0];       // IN_C = 1
  const int Eg   = in_sizes[1] / 2;
  const int Etot = Eg + N;
  const int* esrc = ei;
  const int* edst = ei + Eg;

  char* w = (char*)d_ws;
  auto carve = [&](size_t bytes)->char*{
    char* p = w; w += (bytes + 15) & ~size_t(15); return p;
  };
  float* hbuf   = (float*)carve((size_t)N * 128 * 4);
  float* actA   = (float*)carve((size_t)N * 128 * 4);
  float* asb    = (float*)carve((size_t)N * 4 * 4);
  float* adb    = (float*)carve((size_t)N * 4 * 4);
  float* h3b    = (float*)carve((size_t)N * 4);
  float* as3b   = (float*)carve((size_t)N * 4);
  float* ad3b   = (float*)carve((size_t)N * 4);
  int*   deg    = (int*)  carve((size_t)N * 4);
  int*   rowp   = (int*)  carve((size_t)(N + 1) * 4);
  int*   cursor = (int*)  carve((size_t)N * 4);
  int*   csr_src= (int*)  carve((size_t)Etot * 4);
  float* dAdD   = (float*)carve(8 * 4);
  int*   bsum   = (int*)  carve(64 * 4);
  int*   boff   = (int*)  carve(64 * 4);

  const int B = 256;
  auto cdiv = [](int a, int b){ return (a + b - 1) / b; };
  const int nb = cdiv(N, 2048);   // 25 for N=50000 (must be <= 64)

  // ---- CSR build (shared by all 3 layers) ----
  hipMemsetAsync(deg, 0, (size_t)N * 4, stream);
  hist_k<<<cdiv(Etot, B), B, 0, stream>>>(edst, deg, Eg, Etot);
  scan_part_k<<<nb, B, 0, stream>>>(deg, bsum, N);
  scan_tops_k<<<1, 64, 0, stream>>>(bsum, boff, rowp, nb, N);
  scan_write_k<<<nb, B, 0, stream>>>(deg, boff, rowp, cursor, N);
  scatter_k<<<cdiv(Etot, B), B, 0, stream>>>(esrc, edst, cursor, csr_src, Eg, Etot);

  // ---- layer 1 (rank-1: no transform, scalar gather) ----
  dots1_k<<<1, 128, 0, stream>>>(W1, as1, ad1, dAdD);
  node_aggr1_k<<<cdiv(N, 8), B, 0, stream>>>(rowp, csr_src, x, dAdD,
                                             (const float4*)W1, (const float4*)b1,
                                             (float4*)actA, N);

  // ---- layer 2 ----
  gemm2_k<<<cdiv(N, 64), B, 0, stream>>>(actA, W2, as2, ad2, hbuf, asb, adb, N);
  node_aggr2_k<true><<<cdiv(N, 64) * 8, B, 0, stream>>>(rowp, csr_src, asb, adb,
                                                        (const float4*)hbuf, (const float4*)b2,
                                                        (float4*)actA, N);

  // ---- layer 3 (H=1, C=1) ----
  transform3_k<<<cdiv(N, 8), B, 0, stream>>>(actA, W3, as3, ad3, h3b, as3b, ad3b, N);
  node_aggr3_k<<<cdiv(N, 4), B, 0, stream>>>(rowp, csr_src, as3b, ad3b, h3b, b3, (float*)d_out, N);
}

// Round 8
// 299.706 us; speedup vs baseline: 1.0815x; 1.0527x over previous
//
#include <hip/hip_runtime.h>
#include <math.h>

#define NEG_SLOPE 0.2f

static __device__ __forceinline__ float leaky(float v){ return v > 0.f ? v : NEG_SLOPE * v; }

// ---------------- CSR build (XCD-range-partitioned) ----------------
// slot = blockIdx&7 → XCD (dispatch %8 heuristic). Each slot owns dst range
// [slot*N/8,(slot+1)*N/8): deg/cursor/csr lines are touched by ONE XCD only.
__global__ void __launch_bounds__(256) hist_k(const int* __restrict__ edst, int* __restrict__ deg,
                                              int Eg, int Etot, int N){
  const int slot = blockIdx.x & 7;
  const int lo = (int)(((long long)slot * N) >> 3);
  const int hi = (int)(((long long)(slot + 1) * N) >> 3);
  const int stride = (gridDim.x >> 3) * blockDim.x;
  for (int e = (blockIdx.x >> 3) * blockDim.x + threadIdx.x; e < Etot; e += stride){
    int d = (e < Eg) ? edst[e] : (e - Eg);
    if (d >= lo && d < hi) atomicAdd(&deg[d], 1);
  }
}

__global__ void __launch_bounds__(256) scatter_k(const int* __restrict__ esrc, const int* __restrict__ edst,
                                                 int* __restrict__ cursor, int* __restrict__ csr_src,
                                                 int Eg, int Etot, int N){
  const int slot = blockIdx.x & 7;
  const int lo = (int)(((long long)slot * N) >> 3);
  const int hi = (int)(((long long)(slot + 1) * N) >> 3);
  const int stride = (gridDim.x >> 3) * blockDim.x;
  for (int e = (blockIdx.x >> 3) * blockDim.x + threadIdx.x; e < Etot; e += stride){
    int s, d;
    if (e < Eg){ d = edst[e]; if (d < lo || d >= hi) continue; s = esrc[e]; }
    else { s = d = e - Eg; if (d < lo || d >= hi) continue; }
    int pos = atomicAdd(&cursor[d], 1);
    csr_src[pos] = s;
  }
}

// A: per-block sums (2048 elems / 256-thread block)
__global__ void __launch_bounds__(256) scan_part_k(const int* __restrict__ deg,
                                                   int* __restrict__ bsum, int N){
  __shared__ int red[256];
  const int t = threadIdx.x;
  const int base = blockIdx.x * 2048;
  int sum = 0;
  #pragma unroll
  for (int i = 0; i < 8; ++i){
    int idx = base + t + i * 256;
    if (idx < N) sum += deg[idx];
  }
  red[t] = sum; __syncthreads();
  #pragma unroll
  for (int d = 128; d; d >>= 1){
    if (t < d) red[t] += red[t + d];
    __syncthreads();
  }
  if (t == 0) bsum[blockIdx.x] = red[0];
}

// B: one wave scans the block sums (nb <= 64)
__global__ void scan_tops_k(const int* __restrict__ bsum, int* __restrict__ boff,
                            int* __restrict__ row, int nb, int N){
  int t = threadIdx.x;
  int v = (t < nb) ? bsum[t] : 0;
  int orig = v;
  #pragma unroll
  for (int off = 1; off < 64; off <<= 1){
    int u = __shfl_up(v, off, 64);
    if (t >= off) v += u;
  }
  if (t < nb) boff[t] = v - orig;
  if (t == nb - 1) row[N] = v;
}

// C: per-block local exclusive scan + global offset, write row & cursor
__global__ void __launch_bounds__(256) scan_write_k(const int* __restrict__ deg,
                                                    const int* __restrict__ boff,
                                                    int* __restrict__ row, int* __restrict__ cursor, int N){
  __shared__ int sdeg[2048];
  __shared__ int tsum[256];
  const int t = threadIdx.x;
  const int base = blockIdx.x * 2048;
  for (int i = t; i < 2048; i += 256){
    int idx = base + i;
    sdeg[i] = (idx < N) ? deg[idx] : 0;
  }
  __syncthreads();
  const int off = t * 8;
  int sum = 0;
  #pragma unroll
  for (int i = 0; i < 8; ++i) sum += sdeg[off + i];
  tsum[t] = sum; __syncthreads();
  for (int d = 1; d < 256; d <<= 1){
    int v = (t >= d) ? tsum[t - d] : 0;
    __syncthreads();
    tsum[t] += v;
    __syncthreads();
  }
  int run = boff[blockIdx.x] + ((t == 0) ? 0 : tsum[t - 1]);
  #pragma unroll
  for (int i = 0; i < 8; ++i){
    int idx = base + off + i;
    if (idx < N){ row[idx] = run; cursor[idx] = run; run += sdeg[off + i]; }
  }
}

// ---------------- layer 1 (Fin = 1, rank-1) ----------------
__global__ void dots1_k(const float* __restrict__ W1, const float* __restrict__ a_s,
                        const float* __restrict__ a_d, float* __restrict__ dAdD){
  int t = threadIdx.x;
  float ps = W1[t] * a_s[t];
  float pd = W1[t] * a_d[t];
  #pragma unroll
  for (int off = 16; off; off >>= 1){
    ps += __shfl_xor(ps, off, 32);
    pd += __shfl_xor(pd, off, 32);
  }
  if ((t & 31) == 0){ dAdD[t >> 5] = ps; dAdD[4 + (t >> 5)] = pd; }
}

// Rank-1 layer-1 GAT: out[n][h*32+c] = W1[h*32+c] * (sum_e p_e x[src_e])/s_h + b1, ELU.
__global__ void __launch_bounds__(256) node_aggr1_k(const int* __restrict__ row, const int* __restrict__ csr_src,
                                                    const float* __restrict__ x, const float* __restrict__ dAdD,
                                                    const float4* __restrict__ W1_4, const float4* __restrict__ b1_4,
                                                    float4* __restrict__ out4, int N){
  int node = blockIdx.x * 8 + (threadIdx.x >> 5);
  if (node >= N) return;
  const int j = threadIdx.x & 31;
  const int start = row[node], end = row[node + 1];
  const float xd = x[node];
  float dA0 = dAdD[0], dA1 = dAdD[1], dA2 = dAdD[2], dA3 = dAdD[3];
  float e0d = xd * dAdD[4], e1d = xd * dAdD[5], e2d = xd * dAdD[6], e3d = xd * dAdD[7];

  float s0 = 0.f, s1 = 0.f, s2 = 0.f, s3 = 0.f;
  float t0 = 0.f, t1 = 0.f, t2 = 0.f, t3 = 0.f;
  for (int i = start + j; i < end; i += 32){
    float xs = x[csr_src[i]];
    float p0 = __expf(leaky(xs * dA0 + e0d));
    float p1 = __expf(leaky(xs * dA1 + e1d));
    float p2 = __expf(leaky(xs * dA2 + e2d));
    float p3 = __expf(leaky(xs * dA3 + e3d));
    s0 += p0; s1 += p1; s2 += p2; s3 += p3;
    t0 += p0 * xs; t1 += p1 * xs; t2 += p2 * xs; t3 += p3 * xs;
  }
  #pragma unroll
  for (int off = 16; off; off >>= 1){
    s0 += __shfl_xor(s0, off, 32); t0 += __shfl_xor(t0, off, 32);
    s1 += __shfl_xor(s1, off, 32); t1 += __shfl_xor(t1, off, 32);
    s2 += __shfl_xor(s2, off, 32); t2 += __shfl_xor(t2, off, 32);
    s3 += __shfl_xor(s3, off, 32); t3 += __shfl_xor(t3, off, 32);
  }
  const int hd = j >> 3;
  float r = (hd == 0) ? t0 / s0 : (hd == 1) ? t1 / s1 : (hd == 2) ? t2 / s2 : t3 / s3;
  float4 w = W1_4[j], b = b1_4[j];
  float4 v;
  v.x = w.x * r + b.x;
  v.y = w.y * r + b.y;
  v.z = w.z * r + b.z;
  v.w = w.w * r + b.w;
  v.x = v.x > 0.f ? v.x : expm1f(v.x);
  v.y = v.y > 0.f ? v.y : expm1f(v.y);
  v.z = v.z > 0.f ? v.z : expm1f(v.z);
  v.w = v.w > 0.f ? v.w : expm1f(v.w);
  out4[(size_t)node * 32 + j] = v;
}

// ---------------- per-node aggregate, layer 2: HEAD-SPLIT + XCD-pinned ----------------
// grid.x = cdiv(N,64)*8. slot = blockIdx&7 → XCD; head = slot>>1, parity = slot&1.
// as_/ad_ are HEAD-MAJOR [4][N] so each XCD only touches its head's 200 KB column.
template<bool DO_ELU>
__global__ void __launch_bounds__(256) node_aggr2_k(const int* __restrict__ row, const int* __restrict__ csr_src,
                                                    const float* __restrict__ as_, const float* __restrict__ ad_,
                                                    const float4* __restrict__ h4, const float4* __restrict__ bias4,
                                                    float4* __restrict__ out4, int N){
  const int slot   = blockIdx.x & 7;
  const int chunk  = blockIdx.x >> 3;
  const int head   = slot >> 1;
  const int parity = slot & 1;
  const int t  = threadIdx.x;
  const int nl = t >> 3;          // node slot 0..31
  const int q  = t & 7;           // lane within head
  const int node = chunk * 64 + parity * 32 + nl;
  if (node >= N) return;
  const int start = row[node], end = row[node + 1];
  const float* __restrict__ ash = as_ + (size_t)head * N;
  const float adv = ad_[(size_t)head * N + node];
  const int cix = head * 8 + q;   // float4 index within a 32-float4 row

  float s = 0.f;
  float4 acc = make_float4(0.f, 0.f, 0.f, 0.f);
  int i = start;

  // prologue: align i to a multiple of 4 (csr_src is 16B-aligned)
  int pre = (4 - (start & 3)) & 3;
  if (pre > end - start) pre = end - start;
  for (int k = 0; k < pre; ++k, ++i){
    int src = csr_src[i];
    float p = __expf(leaky(ash[src] + adv));
    float4 hv = h4[(size_t)src*32 + cix];
    s += p;
    acc.x += hv.x*p; acc.y += hv.y*p; acc.z += hv.z*p; acc.w += hv.w*p;
  }
  // main: 4 edges per iter, int4 idx load, gathers batched
  for (; i + 4 <= end; i += 4){
    int4 ia = *(const int4*)&csr_src[i];
    float a0 = ash[ia.x], a1 = ash[ia.y], a2 = ash[ia.z], a3 = ash[ia.w];
    float4 h0 = h4[(size_t)ia.x*32 + cix];
    float4 h1 = h4[(size_t)ia.y*32 + cix];
    float4 h2 = h4[(size_t)ia.z*32 + cix];
    float4 h3 = h4[(size_t)ia.w*32 + cix];
    float p0 = __expf(leaky(a0 + adv));
    float p1 = __expf(leaky(a1 + adv));
    float p2 = __expf(leaky(a2 + adv));
    float p3 = __expf(leaky(a3 + adv));
    s += (p0 + p1) + (p2 + p3);
    acc.x += h0.x*p0 + h1.x*p1 + h2.x*p2 + h3.x*p3;
    acc.y += h0.y*p0 + h1.y*p1 + h2.y*p2 + h3.y*p3;
    acc.z += h0.z*p0 + h1.z*p1 + h2.z*p2 + h3.z*p3;
    acc.w += h0.w*p0 + h1.w*p1 + h2.w*p2 + h3.w*p3;
  }
  // tail
  for (; i < end; ++i){
    int src = csr_src[i];
    float p = __expf(leaky(ash[src] + adv));
    float4 hv = h4[(size_t)src*32 + cix];
    s += p;
    acc.x += hv.x*p; acc.y += hv.y*p; acc.z += hv.z*p; acc.w += hv.w*p;
  }

  float inv = 1.f / s;
  float4 b = bias4[cix];
  float4 v;
  v.x = acc.x * inv + b.x;
  v.y = acc.y * inv + b.y;
  v.z = acc.z * inv + b.z;
  v.w = acc.w * inv + b.w;
  if (DO_ELU){
    v.x = v.x > 0.f ? v.x : expm1f(v.x);
    v.y = v.y > 0.f ? v.y : expm1f(v.y);
    v.z = v.z > 0.f ? v.z : expm1f(v.z);
    v.w = v.w > 0.f ? v.w : expm1f(v.w);
  }
  out4[(size_t)node * 32 + cix] = v;
}

// ---------------- layer 2 dense: h = A(Nx128) * W(128x128), alphas fused ----------------
// as_/ad_ outputs are head-major [4][N].
__global__ void __launch_bounds__(256) gemm2_k(const float* __restrict__ A, const float* __restrict__ W,
                                               const float* __restrict__ a_s, const float* __restrict__ a_d,
                                               float* __restrict__ h, float* __restrict__ as_, float* __restrict__ ad_,
                                               int N){
  __shared__ float sA[2][16][68];    // [buf][k][row] transposed, padded
  __shared__ float sW[2][16][128];   // [buf][k][col]
  const int t = threadIdx.x;
  const int n0 = blockIdx.x * 64;
  const int tx = t & 15, ty = t >> 4;
  const int c0 = tx * 8, r0 = ty * 4;

  const int lr = t >> 2;         // 0..63: A row within tile
  const int lg = t & 3;          // A k-quad
  const int wk = t >> 5;         // 0..7: W k row
  const int wq = t & 31;         // W col-quad

  float4 ra, rw0, rw1;
  const int grA = n0 + lr;
  auto gload = [&](int k0){
    ra  = (grA < N) ? *(const float4*)&A[(size_t)grA * 128 + k0 + lg * 4] : make_float4(0.f,0.f,0.f,0.f);
    rw0 = *(const float4*)&W[(size_t)(k0 + wk) * 128 + wq * 4];
    rw1 = *(const float4*)&W[(size_t)(k0 + wk + 8) * 128 + wq * 4];
  };
  auto sstore = [&](int buf){
    sA[buf][lg*4 + 0][lr] = ra.x;
    sA[buf][lg*4 + 1][lr] = ra.y;
    sA[buf][lg*4 + 2][lr] = ra.z;
    sA[buf][lg*4 + 3][lr] = ra.w;
    *(float4*)&sW[buf][wk][wq*4]     = rw0;
    *(float4*)&sW[buf][wk + 8][wq*4] = rw1;
  };

  float acc[4][8];
  #pragma unroll
  for (int r = 0; r < 4; ++r)
    #pragma unroll
    for (int c = 0; c < 8; ++c) acc[r][c] = 0.f;

  gload(0); sstore(0); __syncthreads();

  #pragma unroll 1
  for (int tile = 0; tile < 8; ++tile){
    const int buf = tile & 1;
    if (tile < 7) gload((tile + 1) * 16);
    #pragma unroll
    for (int k = 0; k < 16; ++k){
      float4 aa = *(const float4*)&sA[buf][k][r0];
      float4 w0 = *(const float4*)&sW[buf][k][c0];
      float4 w1 = *(const float4*)&sW[buf][k][c0 + 4];
      float av[4] = {aa.x, aa.y, aa.z, aa.w};
      float wv[8] = {w0.x, w0.y, w0.z, w0.w, w1.x, w1.y, w1.z, w1.w};
      #pragma unroll
      for (int r = 0; r < 4; ++r)
        #pragma unroll
        for (int c = 0; c < 8; ++c) acc[r][c] += av[r] * wv[c];
    }
    if (tile < 7){ sstore(1 - buf); __syncthreads(); }
  }

  float asv[8], adv[8];
  #pragma unroll
  for (int c = 0; c < 8; ++c){ asv[c] = a_s[c0 + c]; adv[c] = a_d[c0 + c]; }

  #pragma unroll
  for (int r = 0; r < 4; ++r){
    int n = n0 + r0 + r;
    if (n >= N) continue;
    float4 o0 = make_float4(acc[r][0], acc[r][1], acc[r][2], acc[r][3]);
    float4 o1 = make_float4(acc[r][4], acc[r][5], acc[r][6], acc[r][7]);
    float4* hp = (float4*)&h[(size_t)n * 128 + c0];
    hp[0] = o0; hp[1] = o1;
    float ps = 0.f, pd = 0.f;
    #pragma unroll
    for (int c = 0; c < 8; ++c){ ps += acc[r][c] * asv[c]; pd += acc[r][c] * adv[c]; }
    ps += __shfl_xor(ps, 1); ps += __shfl_xor(ps, 2);
    pd += __shfl_xor(pd, 1); pd += __shfl_xor(pd, 2);
    if ((tx & 3) == 0){
      as_[(size_t)(tx >> 2) * N + n] = ps;   // head-major
      ad_[(size_t)(tx >> 2) * N + n] = pd;
    }
  }
}

// ---------------- layer 3 ----------------
__global__ void __launch_bounds__(256) transform3_k(const float* __restrict__ A, const float* __restrict__ W3,
                                                    const float* __restrict__ a_s3, const float* __restrict__ a_d3,
                                                    float* __restrict__ h3, float* __restrict__ as_, float* __restrict__ ad_,
                                                    int N){
  int node = blockIdx.x * 8 + (threadIdx.x >> 5);
  if (node >= N) return;
  int j = threadIdx.x & 31;
  float4 a = ((const float4*)A)[(size_t)node * 32 + j];
  float4 w = ((const float4*)W3)[j];
  float acc = a.x * w.x + a.y * w.y + a.z * w.z + a.w * w.w;
  #pragma unroll
  for (int off = 16; off; off >>= 1) acc += __shfl_xor(acc, off, 32);
  if (j == 0){
    h3[node]  = acc;
    as_[node] = acc * a_s3[0];
    ad_[node] = acc * a_d3[0];
  }
}

// single pass, no max, 64 lanes per node
__global__ void __launch_bounds__(256) node_aggr3_k(const int* __restrict__ row, const int* __restrict__ csr_src,
                                                    const float* __restrict__ as_, const float* __restrict__ ad_,
                                                    const float* __restrict__ h3, const float* __restrict__ b3,
                                                    float* __restrict__ out, int N){
  int node = blockIdx.x * 4 + (threadIdx.x >> 6);
  if (node >= N) return;
  int j = threadIdx.x & 63;
  int start = row[node], end = row[node + 1];
  float adv = ad_[node];
  float s = 0.f, acc = 0.f;
  for (int i = start + j; i < end; i += 64){
    int src = csr_src[i];
    float p = __expf(leaky(as_[src] + adv));
    s += p; acc += h3[src] * p;
  }
  #pragma unroll
  for (int off = 32; off; off >>= 1){ s += __shfl_xor(s, off); acc += __shfl_xor(acc, off); }
  if (j == 0) out[node] = acc / s + b3[0];
}

// ---------------- launch ----------------
extern "C" void kernel_launch(void* const* d_in, const int* in_sizes, int n_in,
                              void* d_out, int out_size, void* d_ws, size_t ws_size,
                              hipStream_t stream){
  const float* x   = (const float*)d_in[0];
  const int*   ei  = (const int*)  d_in[1];
  const float* W1  = (const float*)d_in[2];
  const float* as1 = (const float*)d_in[3];
  const float* ad1 = (const float*)d_in[4];
  const float* b1  = (const float*)d_in[5];
  const float* W2  = (const float*)d_in[6];
  const float* as2 = (const float*)d_in[7];
  const float* ad2 = (const float*)d_in[8];
  const float* b2  = (const float*)d_in[9];
  const float* W3  = (const float*)d_in[10];
  const float* as3 = (const float*)d_in[11];
  const float* ad3 = (const float*)d_in[12];
  const float* b3  = (const float*)d_in[13];

  const int N    = in_sizes[0];       // IN_C = 1
  const int Eg   = in_sizes[1] / 2;
  const int Etot = Eg + N;
  const int* esrc = ei;
  const int* edst = ei + Eg;

  char* w = (char*)d_ws;
  auto carve = [&](size_t bytes)->char*{
    char* p = w; w += (bytes + 15) & ~size_t(15); return p;
  };
  float* hbuf   = (float*)carve((size_t)N * 128 * 4);
  float* actA   = (float*)carve((size_t)N * 128 * 4);
  float* asb    = (float*)carve((size_t)N * 4 * 4);   // head-major [4][N]
  float* adb    = (float*)carve((size_t)N * 4 * 4);   // head-major [4][N]
  float* h3b    = (float*)carve((size_t)N * 4);
  float* as3b   = (float*)carve((size_t)N * 4);
  float* ad3b   = (float*)carve((size_t)N * 4);
  int*   deg    = (int*)  carve((size_t)N * 4);
  int*   rowp   = (int*)  carve((size_t)(N + 1) * 4);
  int*   cursor = (int*)  carve((size_t)N * 4);
  int*   csr_src= (int*)  carve((size_t)Etot * 4);
  float* dAdD   = (float*)carve(8 * 4);
  int*   bsum   = (int*)  carve(64 * 4);
  int*   boff   = (int*)  carve(64 * 4);

  const int B = 256;
  auto cdiv = [](int a, int b){ return (a + b - 1) / b; };
  const int nb = cdiv(N, 2048);   // 25 for N=50000 (must be <= 64)

  // ---- CSR build (shared by all 3 layers) ----
  hipMemsetAsync(deg, 0, (size_t)N * 4, stream);
  hist_k<<<128 * 8, B, 0, stream>>>(edst, deg, Eg, Etot, N);
  scan_part_k<<<nb, B, 0, stream>>>(deg, bsum, N);
  scan_tops_k<<<1, 64, 0, stream>>>(bsum, boff, rowp, nb, N);
  scan_write_k<<<nb, B, 0, stream>>>(deg, boff, rowp, cursor, N);
  scatter_k<<<128 * 8, B, 0, stream>>>(esrc, edst, cursor, csr_src, Eg, Etot, N);

  // ---- layer 1 (rank-1: no transform, scalar gather) ----
  dots1_k<<<1, 128, 0, stream>>>(W1, as1, ad1, dAdD);
  node_aggr1_k<<<cdiv(N, 8), B, 0, stream>>>(rowp, csr_src, x, dAdD,
                                             (const float4*)W1, (const float4*)b1,
                                             (float4*)actA, N);

  // ---- layer 2 ----
  gemm2_k<<<cdiv(N, 64), B, 0, stream>>>(actA, W2, as2, ad2, hbuf, asb, adb, N);
  node_aggr2_k<true><<<cdiv(N, 64) * 8, B, 0, stream>>>(rowp, csr_src, asb, adb,
                                                        (const float4*)hbuf, (const float4*)b2,
                                                        (float4*)actA, N);

  // ---- layer 3 (H=1, C=1) ----
  transform3_k<<<cdiv(N, 8), B, 0, stream>>>(actA, W3, as3, ad3, h3b, as3b, ad3b, N);
  node_aggr3_k<<<cdiv(N, 4), B, 0, stream>>>(rowp, csr_src, as3b, ad3b, h3b, b3, (float*)d_out, N);
}